// Round 1
// 5347.832 us; speedup vs baseline: 1.0480x; 1.0480x over previous
//
#include <hip/hip_runtime.h>
#include <math.h>

#define NDIM 64
#define PITCH 68          // chunk-row pitch in words: float4-aligned, conflict-free
#define KC 16             // columns staged per reconstruction chunk
#define MAXSWEEPS 20

// One wave (64 lanes) per 64x64 SPD matrix. Lane j owns column j in registers.
// One-sided (Hestenes) Jacobi, XOR pair ordering, alternating direction per sweep.
// This revision targets the VALU-issue bound seen in rocprof (VALUBusy ~70%,
// everything else idle): packed fp32 (v_pk_fma_f32 / v_pk_mul_f32, 2 elems/lane
// per instr, emitted via inline asm since hipcc won't form VOP3P fp32 from scalar
// code) on all column-length loops, a division-free rotation-parameter chain
// (t = sign(d)*w/(|d|+sqrt(w^2+d^2)) with single-instr rcp/sqrt/rsq instead of
// two IEEE divides), and one convergence ballot per sweep instead of per rotation.
typedef float v2f __attribute__((ext_vector_type(2)));

__device__ __forceinline__ v2f pk_fma(v2f a, v2f b, v2f c)
{
    v2f d;
    asm("v_pk_fma_f32 %0, %1, %2, %3" : "=v"(d) : "v"(a), "v"(b), "v"(c));
    return d;
}

__device__ __forceinline__ v2f pk_mul(v2f a, v2f b)
{
    v2f d;
    asm("v_pk_mul_f32 %0, %1, %2" : "=v"(d) : "v"(a), "v"(b));
    return d;
}

__global__ __launch_bounds__(64, 3)
void logeig_jacobi_kernel(const float* __restrict__ in, float* __restrict__ out)
{
    const int b    = blockIdx.x;
    const int lane = threadIdx.x;
    const float* A = in  + (size_t)b * (NDIM * NDIM);
    float*       O = out + (size_t)b * (NDIM * NDIM);

    __shared__ float ldsM[KC * PITCH];   // 16 staged columns (column j -> row j-c)
    __shared__ float ldsW[NDIM];         // per-column weights

    // stage in: column 'lane' of A, packed as 32 float2 pairs; coalesced across lanes
    v2f x2[NDIM / 2];
#pragma unroll
    for (int i = 0; i < NDIM / 2; ++i) {
        x2[i].x = A[(2 * i + 0) * NDIM + lane];
        x2[i].y = A[(2 * i + 1) * NDIM + lane];
    }

    float alpha = 0.0f;   // refreshed at each sweep start before first use

#pragma unroll 1
    for (int sweep = 0; sweep < MAXSWEEPS; ++sweep) {
        // refresh self-dot (kills incremental-update drift); packed, 2 chains
        v2f r0 = {0.f, 0.f}, r1 = {0.f, 0.f};
#pragma unroll
        for (int i = 0; i < NDIM / 2; i += 2) {
            r0 = pk_fma(x2[i],     x2[i],     r0);
            r1 = pk_fma(x2[i + 1], x2[i + 1], r1);
        }
        alpha = (r0.x + r0.y) + (r1.x + r1.y);

        bool any_big = false;   // per-lane; one ballot per sweep
#pragma unroll 1
        for (int mi = 1; mi < NDIM; ++mi) {
            const int m    = (sweep & 1) ? (NDIM - mi) : mi;  // alternate direction
            const int pidx = (lane ^ m) << 2;

            // pull partner column (64 b32 bpermutes)
            v2f y2[NDIM / 2];
#pragma unroll
            for (int i = 0; i < NDIM / 2; ++i) {
                y2[i].x = __int_as_float(__builtin_amdgcn_ds_bpermute(pidx, __float_as_int(x2[i].x)));
                y2[i].y = __int_as_float(__builtin_amdgcn_ds_bpermute(pidx, __float_as_int(x2[i].y)));
            }

            // cross dot, packed, 2 chains; product order identical on both lanes
            // of a pair (mult commutes, same grouping) -> bitwise-same gamma
            v2f g0 = {0.f, 0.f}, g1 = {0.f, 0.f};
#pragma unroll
            for (int i = 0; i < NDIM / 2; i += 2) {
                g0 = pk_fma(x2[i],     y2[i],     g0);
                g1 = pk_fma(x2[i + 1], y2[i + 1], g1);
            }
            const float gamma = (g0.x + g0.y) + (g1.x + g1.y);

            const float other = __int_as_float(__builtin_amdgcn_ds_bpermute(pidx, __float_as_int(alpha)));

            const bool  is_p = lane < (lane ^ m);
            const float aa = is_p ? alpha : other;  // alpha (p's self-dot)
            const float bb = is_p ? other : alpha;  // beta  (q's self-dot)

            // convergence detector ONLY (rel 3.2e-5 > fp32 dot noise ~5e-7);
            // does not gate the rotation -> no stagnation
            any_big = any_big || ((gamma * gamma) > (1e-9f * aa * bb));

            // Golub-Van-Loan symmetric Schur, division-free:
            //   w = 2*gamma, d = bb-aa
            //   t = sign(d)*w / (|d| + sqrt(w^2 + d^2))   (== sign(z)/(|z|+sqrt(1+z^2)))
            // 1e-35 floor inside the sqrt keeps the w-denormal/d==0 corner finite;
            // w,d identical on both lanes of a pair -> bitwise-same t,c,s.
            const bool  rot = (gamma != 0.0f);
            const float w   = 2.0f * gamma;
            const float d   = bb - aa;
            const float den = fabsf(d) + __builtin_amdgcn_sqrtf(fmaf(w, w, fmaf(d, d, 1e-35f)));
            const float t   = ((d >= 0.0f) ? w : -w) * __builtin_amdgcn_rcpf(den);
            const float cc  = __builtin_amdgcn_rsqf(fmaf(t, t, 1.0f));
            const float ss  = t * cc;

            const float sgn = is_p ? -1.0f : 1.0f;  // p: x' = c x - s y ; q: x' = c x + s y
            const float c_r = rot ? cc : 1.0f;
            const float s_r = rot ? sgn * ss : 0.0f;
            const float tg  = rot ? sgn * t * gamma : 0.0f;

            v2f c2; c2.x = c_r; c2.y = c_r;
            v2f s2; s2.x = s_r; s2.y = s_r;
#pragma unroll
            for (int i = 0; i < NDIM / 2; ++i)
                x2[i] = pk_fma(c2, x2[i], pk_mul(s2, y2[i]));
            alpha += tg;                            // alpha' = alpha -/+ t*gamma
        }
        if (__ballot(any_big) == 0ull) break;   // all pairs below rel 3.2e-5 -> converged
    }

    // eigenvalue & weight: lambda = ||m||, w = log(lambda + 1e-9) / lambda^2
    v2f f0 = {0.f, 0.f}, f1 = {0.f, 0.f};
#pragma unroll
    for (int i = 0; i < NDIM / 2; i += 2) {
        f0 = pk_fma(x2[i],     x2[i],     f0);
        f1 = pk_fma(x2[i + 1], x2[i + 1], f1);
    }
    const float af  = (f0.x + f0.y) + (f1.x + f1.y);
    const float lam = __builtin_amdgcn_sqrtf(af);
    ldsW[lane] = logf(lam + 1e-9f) / af;   // first __syncthreads below orders this

    // O[:,lane] = sum_k (w_k * m_{lane,k}) * m_{:,k}, staged KC columns at a time
    v2f acc2[NDIM / 2];
#pragma unroll
    for (int i = 0; i < NDIM / 2; ++i) { acc2[i].x = 0.f; acc2[i].y = 0.f; }

#pragma unroll 1
    for (int c = 0; c < NDIM; c += KC) {
        __syncthreads();   // prev chunk fully read (and ldsW visible on c==0)
        if (lane >= c && lane < c + KC) {
            float4* row = (float4*)&ldsM[(lane - c) * PITCH];
#pragma unroll
            for (int t4 = 0; t4 < NDIM / 4; ++t4)
                row[t4] = make_float4(x2[2 * t4].x, x2[2 * t4].y,
                                      x2[2 * t4 + 1].x, x2[2 * t4 + 1].y);
        }
        __syncthreads();
#pragma unroll 1
        for (int kk = 0; kk < KC; ++kk) {
            const float wk  = ldsW[c + kk];             // broadcast
            const float mlk = ldsM[kk * PITCH + lane];  // consecutive -> conflict-free
            const float zk  = wk * mlk;
            v2f zk2; zk2.x = zk; zk2.y = zk;
            const float4* rowk = (const float4*)&ldsM[kk * PITCH];
#pragma unroll
            for (int t4 = 0; t4 < NDIM / 4; ++t4) {
                const float4 v = rowk[t4];              // broadcast float4
                v2f lo; lo.x = v.x; lo.y = v.y;
                v2f hi; hi.x = v.z; hi.y = v.w;
                acc2[2 * t4]     = pk_fma(zk2, lo, acc2[2 * t4]);
                acc2[2 * t4 + 1] = pk_fma(zk2, hi, acc2[2 * t4 + 1]);
            }
        }
    }

#pragma unroll
    for (int i = 0; i < NDIM / 2; ++i) {
        O[(2 * i + 0) * NDIM + lane] = acc2[i].x;   // coalesced across lanes
        O[(2 * i + 1) * NDIM + lane] = acc2[i].y;
    }
}

extern "C" void kernel_launch(void* const* d_in, const int* in_sizes, int n_in,
                              void* d_out, int out_size, void* d_ws, size_t ws_size,
                              hipStream_t stream)
{
    const float* in  = (const float*)d_in[0];
    float*       out = (float*)d_out;
    const int nmat = out_size / (NDIM * NDIM);   // 256*32 = 8192
    hipLaunchKernelGGL(logeig_jacobi_kernel, dim3(nmat), dim3(64), 0, stream, in, out);
}